// Round 6
// baseline (176.864 us; speedup 1.0000x reference)
//
#include <hip/hip_runtime.h>

typedef __attribute__((ext_vector_type(8))) short short8;
typedef __attribute__((ext_vector_type(4))) float f32x4;

__device__ __forceinline__ unsigned short bf16rne(float f) {
    unsigned u = __float_as_uint(f);
    u += 0x7FFFu + ((u >> 16) & 1u);
    return (unsigned short)(u >> 16);
}
__device__ __forceinline__ float bf16dec(unsigned short h) {
    return __uint_as_float((unsigned)h << 16);
}
__device__ __forceinline__ unsigned cvtpk2(float lo, float hi) {
    unsigned r;
    asm("v_cvt_pk_bf16_f32 %0, %1, %2" : "=v"(r) : "v"(lo), "v"(hi));
    return r;
}

extern __shared__ char smem[];

// ======================= v5: channel-last patch, no im2col =======================
// K-order for the offset GEMM: kk" = g*144 + tap*16 + cw  (g=c/16, cw=c%16).
// A-fragment (8 consecutive kk", cw0 in {0,8}) = 8 consecutive channels at one
// tap = contiguous b128 read from channel-last patch PT[y][x][c] (stride 66).
// Weights are pre-packed in this K-order by pack_weights (zeros outside window).
//
// LDS map (38656 B -> 4 blocks/CU, 16 waves/CU):
//   PT  [12 y][16 x][66 c] bf16 @0     (25344 B)  halo-4 patch, channel-last
//   SX  [4 jw][32 px][36] bf16 @25344  ( 9216 B)  sampled A-frags (per-wave)
//   LGX [32 px][16 sl][4 j] bf16 @34560 ( 4096 B) softmax logits, b64-readable
//   OTB alias @0 (8448 B, epilogue only)

#define PT5_OFF   0
#define SX5_OFF   25344
#define LGX5_OFF  34560
#define LDS_V5    38656
#define OTB5_OFF  0

#define PWOFF_U32  138240   // 108 tiles * 5 kt * 64 lanes * 4 u32 (16x16x32 B-frags)
#define PWM_U32    5120     // 4 jw * 5 pairs * 64 lanes * 4 u32
#define WS_NEEDED  ((size_t)(PWOFF_U32 + PWM_U32) * 4)

__global__ __launch_bounds__(256)
void pack_weights(const float* __restrict__ wmain,
                  const float* __restrict__ woff,
                  unsigned* __restrict__ pw)
{
    int idx = blockIdx.x * 256 + threadIdx.x;
    if (idx < PWOFF_U32) {
        int j2   = idx & 3;
        int lane = (idx >> 2) & 63;
        int rest = idx >> 8;              // t*5 + kt
        int kt   = rest % 5;
        int t    = rest / 5;
        int comp = t / 36, r36 = t - comp * 36;
        int jw   = r36 / 9, ntg = r36 - jw * 9;
        int ochb = comp * 576 + jw * 144 + ntg * 16;
        int g    = ochb / 432;
        int ktf  = (9 * g) >> 1;
        int och  = ochb + (lane & 15);
        int w    = (ktf + kt) * 32 + (lane >> 4) * 8 + j2 * 2 - g * 144;
        float v0 = 0.f, v1 = 0.f;
        // K-order remap: window element w -> original index cw*9 + tap
        if ((unsigned)w < 144u)
            v0 = woff[(size_t)och * 144 + (w & 15) * 9 + (w >> 4)];
        int w1 = w + 1;
        if ((unsigned)w1 < 144u)
            v1 = woff[(size_t)och * 144 + (w1 & 15) * 9 + (w1 >> 4)];
        pw[idx] = (unsigned)bf16rne(v0) | ((unsigned)bf16rne(v1) << 16);
    } else if (idx < PWOFF_U32 + PWM_U32) {
        int m    = idx - PWOFF_U32;
        int j2   = m & 3;
        int lane = (m >> 2) & 63;
        int rest = m >> 8;                // jw*5 + pair
        int jw   = rest / 5, pair = rest - jw * 5;
        int och  = jw * 16 + (lane & 15);
        int w0   = pair * 32 + (lane >> 4) * 8 + j2 * 2;
        float v0 = (w0 < 144)     ? wmain[(size_t)och * 144 + w0]     : 0.f;
        float v1 = (w0 + 1 < 144) ? wmain[(size_t)och * 144 + w0 + 1] : 0.f;
        pw[idx] = (unsigned)bf16rne(v0) | ((unsigned)bf16rne(v1) << 16);
    }
}

__global__ __launch_bounds__(256, 4)
void deform_v5(const float* __restrict__ inps,
               const float* __restrict__ bmain,
               const float* __restrict__ boff,
               const unsigned short* __restrict__ pwoff,
               const unsigned short* __restrict__ pwm,
               float* __restrict__ out)
{
    unsigned short* PT  = (unsigned short*)(smem + PT5_OFF);
    unsigned short* SX  = (unsigned short*)(smem + SX5_OFF);
    unsigned short* LGX = (unsigned short*)(smem + LGX5_OFF);
    float*          OTB = (float*)(smem + OTB5_OFF);

    const int tid  = threadIdx.x;
    const int lane = tid & 63;
    const int jw   = __builtin_amdgcn_readfirstlane(tid >> 6);
    const int slot = lane & 15;
    const int q    = lane >> 4;
    const int pyr0 = slot >> 3;          // px row for mt=0
    const int pxx0 = slot & 7;

    const int b    = blockIdx.x >> 7;
    const int tile = blockIdx.x & 127;
    const int ty0  = (tile >> 3) << 2;   // 16 y-tiles of 4
    const int tx0  = (tile & 7) << 3;    // 8 x-tiles of 8

    const float* inb = inps + (size_t)b * 262144;

    // ---- phase 1: PT bf16 [12 y][16 x][66 c] halo 4, zero OOB ----
    for (int e = tid; e < 12288; e += 256) {
        int c = e >> 6;                  // wait: need c slow for coalescing; use e/192 split
        // e = c*192 + rem  (rem = y*16+x); consecutive tid -> consecutive x
        c = e / 192;
        int rem = e - c * 192;
        int y = rem >> 4, x = rem & 15;
        int gy = ty0 + y - 4, gx = tx0 + x - 4;
        float v = 0.f;
        if ((unsigned)gy < 64u && (unsigned)gx < 64u)
            v = inb[(c * 64 + gy) * 64 + gx];
        PT[rem * 66 + c] = bf16rne(v);
    }
    __syncthreads();

    f32x4 aco[2] = {{0.f,0.f,0.f,0.f},{0.f,0.f,0.f,0.f}};

    auto pair_mfma = [&](int pair) {
        const short8 bfr = ((const short8*)pwm)[(jw * 5 + pair) * 64 + lane];
        #pragma unroll
        for (int mt = 0; mt < 2; ++mt) {
            const short8 a8 = *(const short8*)(SX + jw * 1152 + (mt * 16 + slot) * 36 + q * 8);
            aco[mt] = __builtin_amdgcn_mfma_f32_16x16x32_bf16(a8, bfr, aco[mt], 0, 0, 0);
        }
    };

    // ---- phase 2: ntg loop ----
    for (int ntg = 0; ntg < 9; ++ntg) {
        f32x4 aD[2] = {{0.f,0.f,0.f,0.f},{0.f,0.f,0.f,0.f}};
        f32x4 aX[2] = {{0.f,0.f,0.f,0.f},{0.f,0.f,0.f,0.f}};
        f32x4 aM[2] = {{0.f,0.f,0.f,0.f},{0.f,0.f,0.f,0.f}};

        auto gemm3 = [&](f32x4* acc, int comp) {
            const int ochb   = comp * 576 + jw * 144 + ntg * 16;
            const int g      = ochb / 432;
            const int ktf    = (9 * g) >> 1;
            const int t      = comp * 36 + jw * 9 + ntg;
            const short8* wp = (const short8*)pwoff + t * 320 + lane;   // + kt*64
            const int w8base = ktf * 32 + q * 8 - g * 144;
            const int gc16   = g * 16;
            #pragma unroll
            for (int kt = 0; kt < 5; ++kt) {
                const short8 bfr = wp[kt * 64];
                int wc = w8base + kt * 32;
                wc = wc < 0 ? 0 : (wc > 136 ? 136 : wc);   // clamp: zero-weight lanes
                const int tap = wc >> 4;
                const int ky  = (tap * 11) >> 5;           // tap/3 for tap<9
                const int kx  = tap - ky * 3;
                const int a0  = ((pyr0 + ky + 3) * 16 + (pxx0 + kx + 3)) * 66
                                + gc16 + (wc & 15);
                const short8 af0 = *(const short8*)(PT + a0);
                const short8 af1 = *(const short8*)(PT + a0 + 2112);   // +2 rows (mt=1)
                acc[0] = __builtin_amdgcn_mfma_f32_16x16x32_bf16(af0, bfr, acc[0], 0, 0, 0);
                acc[1] = __builtin_amdgcn_mfma_f32_16x16x32_bf16(af1, bfr, acc[1], 0, 0, 0);
            }
            const float bo = boff[ochb + slot];
            #pragma unroll
            for (int mt = 0; mt < 2; ++mt) {
                acc[mt][0] += bo; acc[mt][1] += bo; acc[mt][2] += bo; acc[mt][3] += bo;
            }
        };
        gemm3(aD, 0); gemm3(aX, 1); gemm3(aM, 2);

        // logits -> LGX[px][slot][j] (cross-wave)
        #pragma unroll
        for (int mt = 0; mt < 2; ++mt)
        #pragma unroll
        for (int r = 0; r < 4; ++r) {
            int pxr = mt * 16 + q * 4 + r;
            LGX[pxr * 64 + slot * 4 + jw] = bf16rne(aM[mt][r]);
        }
        __syncthreads();

        // sampling (LDS patch fast path; global fallback for big offsets)
        const int rr  = ntg * 16 + slot;
        const int cg  = rr / 9;
        const int kk9 = rr - cg * 9;
        const int kyk = kk9 / 3, kxk = kk9 - kyk * 3;
        const int c   = jw * 16 + cg;
        const float* inc = inb + c * 4096;
        const int par = ntg & 1;

        #pragma unroll
        for (int mt = 0; mt < 2; ++mt)
        #pragma unroll
        for (int r = 0; r < 4; ++r) {
            const int pxr = mt * 16 + q * 4 + r;
            const int pyr = pxr >> 3, pxx = pxr & 7;
            const float own = aM[mt][r];

            const uint2 lg = *(const uint2*)(LGX + pxr * 64 + slot * 4);
            float s4 = __expf(bf16dec((unsigned short)(lg.x & 0xFFFF)) - own)
                     + __expf(bf16dec((unsigned short)(lg.x >> 16))    - own)
                     + __expf(bf16dec((unsigned short)(lg.y & 0xFFFF)) - own)
                     + __expf(bf16dec((unsigned short)(lg.y >> 16))    - own);
            const float msk = 1.0f / s4;

            float pyf = (float)(ty0 + pyr + kyk - 1) + aD[mt][r];
            float pxf = (float)(tx0 + pxx + kxk - 1) + aX[mt][r];
            float y0f = floorf(pyf), x0f = floorf(pxf);
            float wy = pyf - y0f, wx = pxf - x0f;
            int iy0 = (int)y0f, ix0 = (int)x0f;
            float w00 = (1.f - wy) * (1.f - wx), w01 = (1.f - wy) * wx;
            float w10 = wy * (1.f - wx),         w11 = wy * wx;

            int ly0 = iy0 - ty0 + 4;
            int lx0 = ix0 - tx0 + 4;
            float v;
            if ((unsigned)ly0 < 11u && (unsigned)lx0 < 15u) {
                const int a = (ly0 * 16 + lx0) * 66 + c;
                v = w00 * bf16dec(PT[a])        + w01 * bf16dec(PT[a + 66])
                  + w10 * bf16dec(PT[a + 1056]) + w11 * bf16dec(PT[a + 1122]);
            } else {
                v = 0.f;
                if ((unsigned)iy0 < 64u) {
                    if ((unsigned)ix0 < 64u)       v += w00 * inc[iy0 * 64 + ix0];
                    if ((unsigned)(ix0 + 1) < 64u) v += w01 * inc[iy0 * 64 + ix0 + 1];
                }
                if ((unsigned)(iy0 + 1) < 64u) {
                    if ((unsigned)ix0 < 64u)       v += w10 * inc[(iy0 + 1) * 64 + ix0];
                    if ((unsigned)(ix0 + 1) < 64u) v += w11 * inc[(iy0 + 1) * 64 + ix0 + 1];
                }
            }
            SX[jw * 1152 + pxr * 36 + par * 16 + slot] = bf16rne(v * msk);
        }

        // main-conv partial GEMM every completed pair (same-wave SX -> no barrier)
        if (ntg & 1)  { asm volatile("" ::: "memory"); pair_mfma(ntg >> 1); }
        if (ntg == 8) { asm volatile("" ::: "memory"); pair_mfma(4); }
        __syncthreads();
    }

    // ---- epilogue: transpose via OTB (aliases PT), coalesced store ----
    {
        const int o = jw * 16 + slot;
        const float bo = bmain[o];
        #pragma unroll
        for (int mt = 0; mt < 2; ++mt)
        #pragma unroll
        for (int r = 0; r < 4; ++r)
            OTB[o * 33 + mt * 16 + q * 4 + r] = aco[mt][r] + bo;
    }
    __syncthreads();
    #pragma unroll
    for (int i = 0; i < 8; ++i) {
        int f  = i * 256 + tid;
        int oo = f >> 5, pp = f & 31;
        out[(size_t)(b * 64 + oo) * 4096 + (ty0 + (pp >> 3)) * 64 + (tx0 + (pp & 7))] =
            OTB[oo * 33 + pp];
    }
}

// ======================= v2 fallback (proven, 263 us; no ws needed) =======================
#define V2IMC_OFF   0
#define V2S_OFF     37376
#define V2LGX_OFF   74752
#define V2LDS_BYTES 78848

__global__ __launch_bounds__(256, 2)
void deform_v2(const float* __restrict__ inps,
               const float* __restrict__ wmain,
               const float* __restrict__ bmain,
               const float* __restrict__ woff,
               const float* __restrict__ boff,
               float* __restrict__ out)
{
    unsigned short* IMC  = (unsigned short*)(smem + V2IMC_OFF);
    unsigned short* SBUF = (unsigned short*)(smem + V2S_OFF);
    unsigned short* LGX  = (unsigned short*)(smem + V2LGX_OFF);
    float* PATCH = (float*)(smem + V2S_OFF);
    float* OTB   = (float*)(smem + V2IMC_OFF);

    const int tid  = threadIdx.x;
    const int lane = tid & 63;
    const int jw   = __builtin_amdgcn_readfirstlane(tid >> 6);
    const int slot = lane & 15;
    const int q    = lane >> 4;

    const int b    = blockIdx.x >> 7;
    const int tile = blockIdx.x & 127;
    const int ty0  = (tile >> 3) << 2;
    const int tx0  = (tile & 7) << 3;

    const float* inb = inps + (size_t)b * 262144;

    for (int e = tid; e < 64 * 60; e += 256) {
        int ch = e / 60, rem = e - ch * 60;
        int iy = rem / 10, ix = rem - iy * 10;
        int gy = ty0 + iy - 1, gx = tx0 + ix - 1;
        float v = 0.f;
        if ((unsigned)gy < 64u && (unsigned)gx < 64u)
            v = inb[(ch * 64 + gy) * 64 + gx];
        PATCH[ch * 61 + rem] = v;
    }
    __syncthreads();
    {
        const int px  = tid >> 3;
        const int sub = tid & 7;
        const int pyr = px >> 3, pxx = px & 7;
        unsigned short* dst = IMC + px * 584;
        for (int i = 0; i < 36; ++i) {
            int kk = sub * 72 + 2 * i;
            float v0, v1;
            { int c = kk / 9, r9 = kk - c * 9, ky = r9 / 3, kx = r9 - ky * 3;
              v0 = PATCH[c * 61 + (pyr + ky) * 10 + (pxx + kx)]; }
            { int k1 = kk + 1; int c = k1 / 9, r9 = k1 - c * 9, ky = r9 / 3, kx = r9 - ky * 3;
              v1 = PATCH[c * 61 + (pyr + ky) * 10 + (pxx + kx)]; }
            *(unsigned*)(dst + kk) = cvtpk2(v0, v1);
        }
    }
    __syncthreads();

    for (int ntg = 0; ntg < 9; ++ntg) {
        f32x4 aD[2] = {{0.f,0.f,0.f,0.f},{0.f,0.f,0.f,0.f}};
        f32x4 aX[2] = {{0.f,0.f,0.f,0.f},{0.f,0.f,0.f,0.f}};
        f32x4 aM[2] = {{0.f,0.f,0.f,0.f},{0.f,0.f,0.f,0.f}};

        auto gemm3 = [&](f32x4* acc, int comp) {
            const int ochb = comp * 576 + jw * 144 + ntg * 16;
            const int g    = ochb / 432;
            const int ktf  = (9 * g) >> 1;
            const int ch0  = g * 18;
            const int och  = ochb + slot;
            #pragma unroll
            for (int kt = 0; kt < 5; ++kt) {
                const int ktg   = ktf + kt;
                const int chunk = ktg * 4 + q;
                short8 bfr;
                if ((unsigned)(chunk - ch0) < 18u) {
                    const float4* wp = (const float4*)(woff + (size_t)och * 144 + (chunk - ch0) * 8);
                    float4 w0 = wp[0], w1 = wp[1];
                    union { unsigned u[4]; short8 s; } cv;
                    cv.u[0] = cvtpk2(w0.x, w0.y); cv.u[1] = cvtpk2(w0.z, w0.w);
                    cv.u[2] = cvtpk2(w1.x, w1.y); cv.u[3] = cvtpk2(w1.z, w1.w);
                    bfr = cv.s;
                } else {
                    bfr = short8{0,0,0,0,0,0,0,0};
                }
                #pragma unroll
                for (int mt = 0; mt < 2; ++mt) {
                    const short8* ap = (const short8*)(smem + V2IMC_OFF +
                                        (mt * 16 + slot) * 1168 + ktg * 64 + q * 16);
                    acc[mt] = __builtin_amdgcn_mfma_f32_16x16x32_bf16(*ap, bfr, acc[mt], 0, 0, 0);
                }
            }
            const float bo = boff[ochb + slot];
            #pragma unroll
            for (int mt = 0; mt < 2; ++mt) {
                acc[mt][0] += bo; acc[mt][1] += bo; acc[mt][2] += bo; acc[mt][3] += bo;
            }
        };
        gemm3(aD, 0); gemm3(aX, 1); gemm3(aM, 2);

        #pragma unroll
        for (int mt = 0; mt < 2; ++mt)
        #pragma unroll
        for (int r = 0; r < 4; ++r) {
            int pxr = mt * 16 + q * 4 + r;
            LGX[(jw * 32 + pxr) * 16 + slot] = bf16rne(aM[mt][r]);
        }
        __syncthreads();

        const int rr  = ntg * 16 + slot;
        const int cg  = rr / 9;
        const int kk9 = rr - cg * 9;
        const int kyk = kk9 / 3, kxk = kk9 - kyk * 3;
        const float* inc = inb + (jw * 16 + cg) * 4096;

        #pragma unroll
        for (int mt = 0; mt < 2; ++mt)
        #pragma unroll
        for (int r = 0; r < 4; ++r) {
            const int pxr = mt * 16 + q * 4 + r;
            const int pyr = pxr >> 3, pxx = pxr & 7;
            float own = aM[mt][r];
            float l0 = (jw == 0) ? own : bf16dec(LGX[(0 * 32 + pxr) * 16 + slot]);
            float l1 = (jw == 1) ? own : bf16dec(LGX[(1 * 32 + pxr) * 16 + slot]);
            float l2 = (jw == 2) ? own : bf16dec(LGX[(2 * 32 + pxr) * 16 + slot]);
            float l3 = (jw == 3) ? own : bf16dec(LGX[(3 * 32 + pxr) * 16 + slot]);
            float m4 = fmaxf(fmaxf(l0, l1), fmaxf(l2, l3));
            float s4 = __expf(l0 - m4) + __expf(l1 - m4) + __expf(l2 - m4) + __expf(l3 - m4);
            float msk = __expf(own - m4) / s4;

            float pyf = (float)(ty0 + pyr + kyk - 1) + aD[mt][r];
            float pxf = (float)(tx0 + pxx + kxk - 1) + aX[mt][r];
            float y0f = floorf(pyf), x0f = floorf(pxf);
            float wy = pyf - y0f, wx = pxf - x0f;
            int iy0 = (int)y0f, ix0 = (int)x0f;
            float w00 = (1.f - wy) * (1.f - wx), w01 = (1.f - wy) * wx;
            float w10 = wy * (1.f - wx),         w11 = wy * wx;
            float v = 0.f;
            if ((unsigned)iy0 < 64u) {
                if ((unsigned)ix0 < 64u)       v += w00 * inc[iy0 * 64 + ix0];
                if ((unsigned)(ix0 + 1) < 64u) v += w01 * inc[iy0 * 64 + ix0 + 1];
            }
            if ((unsigned)(iy0 + 1) < 64u) {
                if ((unsigned)ix0 < 64u)       v += w10 * inc[(iy0 + 1) * 64 + ix0];
                if ((unsigned)(ix0 + 1) < 64u) v += w11 * inc[(iy0 + 1) * 64 + ix0 + 1];
            }
            SBUF[pxr * 584 + jw * 144 + rr] = bf16rne(v * msk);
        }
        __syncthreads();
    }

    {
        f32x4 aco2[2] = {{0.f,0.f,0.f,0.f},{0.f,0.f,0.f,0.f}};
        const int ktf = (9 * jw) >> 1;
        const int ch0 = jw * 18;
        const int o   = jw * 16 + slot;
        #pragma unroll
        for (int kt = 0; kt < 5; ++kt) {
            const int ktg   = ktf + kt;
            const int chunk = ktg * 4 + q;
            short8 bfr;
            if ((unsigned)(chunk - ch0) < 18u) {
                const float4* wp = (const float4*)(wmain + (size_t)o * 144 + (chunk - ch0) * 8);
                float4 w0 = wp[0], w1 = wp[1];
                union { unsigned u[4]; short8 s; } cv;
                cv.u[0] = cvtpk2(w0.x, w0.y); cv.u[1] = cvtpk2(w0.z, w0.w);
                cv.u[2] = cvtpk2(w1.x, w1.y); cv.u[3] = cvtpk2(w1.z, w1.w);
                bfr = cv.s;
            } else {
                bfr = short8{0,0,0,0,0,0,0,0};
            }
            #pragma unroll
            for (int mt = 0; mt < 2; ++mt) {
                const short8* ap = (const short8*)(smem + V2S_OFF +
                                    (mt * 16 + slot) * 1168 + ktg * 64 + q * 16);
                aco2[mt] = __builtin_amdgcn_mfma_f32_16x16x32_bf16(*ap, bfr, aco2[mt], 0, 0, 0);
            }
        }
        const float bo = bmain[o];
        __syncthreads();
        #pragma unroll
        for (int mt = 0; mt < 2; ++mt)
        #pragma unroll
        for (int r = 0; r < 4; ++r)
            OTB[o * 33 + mt * 16 + q * 4 + r] = aco2[mt][r] + bo;
    }
    __syncthreads();
    #pragma unroll
    for (int i = 0; i < 8; ++i) {
        int f  = i * 256 + tid;
        int oo = f >> 5, pp = f & 31;
        out[(size_t)(b * 64 + oo) * 4096 + (ty0 + (pp >> 3)) * 64 + (tx0 + (pp & 7))] =
            OTB[oo * 33 + pp];
    }
}

extern "C" void kernel_launch(void* const* d_in, const int* in_sizes, int n_in,
                              void* d_out, int out_size, void* d_ws, size_t ws_size,
                              hipStream_t stream) {
    const float* inps   = (const float*)d_in[0];
    const float* weight = (const float*)d_in[1];
    const float* bias   = (const float*)d_in[2];
    const float* woff   = (const float*)d_in[3];
    const float* boff   = (const float*)d_in[4];
    float* outp = (float*)d_out;

    if (ws_size >= WS_NEEDED) {
        unsigned* pw = (unsigned*)d_ws;
        pack_weights<<<dim3(560), dim3(256), 0, stream>>>(weight, woff, pw);
        hipFuncSetAttribute((const void*)deform_v5,
                            hipFuncAttributeMaxDynamicSharedMemorySize, LDS_V5);
        deform_v5<<<dim3(1024), dim3(256), LDS_V5, stream>>>(
            inps, bias, boff,
            (const unsigned short*)pw,
            (const unsigned short*)(pw + PWOFF_U32), outp);
    } else {
        hipFuncSetAttribute((const void*)deform_v2,
                            hipFuncAttributeMaxDynamicSharedMemorySize, V2LDS_BYTES);
        deform_v2<<<dim3(1024), dim3(256), V2LDS_BYTES, stream>>>(
            inps, weight, bias, woff, boff, outp);
    }
}

// Round 7
// 136.649 us; speedup vs baseline: 1.2943x; 1.2943x over previous
//
#include <hip/hip_runtime.h>

typedef __attribute__((ext_vector_type(8))) short short8;
typedef __attribute__((ext_vector_type(4))) float f32x4;

__device__ __forceinline__ unsigned short bf16rne(float f) {
    unsigned u = __float_as_uint(f);
    u += 0x7FFFu + ((u >> 16) & 1u);
    return (unsigned short)(u >> 16);
}
__device__ __forceinline__ float bf16dec(unsigned short h) {
    return __uint_as_float((unsigned)h << 16);
}
__device__ __forceinline__ unsigned cvtpk2(float lo, float hi) {
    unsigned r;
    asm("v_cvt_pk_bf16_f32 %0, %1, %2" : "=v"(r) : "v"(lo), "v"(hi));
    return r;
}

extern __shared__ char smem[];

// ======================= v6: v4 structure + 1 barrier/ntg =======================
// LDS map (dynamic, 81664 B -> 2 blocks/CU):
//   IMC   [32 px][584] bf16  @0      (37376 B)  im2col A-matrix (static addressing)
//   PATCH [64 ch][12][16]    @37376  (25344 B)  bf16 halo-4 patch, stride 198 sh
//   SX    [4 jw][32][40]     @62720  (10240 B)  sampled A-frags (per-wave)
//   LGX   2 x [32 px][68]    @72960  ( 8704 B)  softmax logits double-buffered;
//                                               [px]*68 + slot*4 + j, b64-readable
//   OTB alias @37376 (8448 B, epilogue only)

#define IMC6_OFF   0
#define PATCH6_OFF 37376
#define SX6_OFF    62720
#define LGX6_OFF   72960
#define LDS_V6     81664
#define OTB6_OFF   37376

#define PWOFF_U32  138240   // 108 tiles * 5 kt * 64 lanes * 4 u32 (16x16x32 B-frags)
#define PWM_U32    5120     // 4 jw * 5 pairs * 64 lanes * 4 u32
#define WS_NEEDED  ((size_t)(PWOFF_U32 + PWM_U32) * 4)

__global__ __launch_bounds__(256)
void pack_weights(const float* __restrict__ wmain,
                  const float* __restrict__ woff,
                  unsigned* __restrict__ pw)
{
    int idx = blockIdx.x * 256 + threadIdx.x;
    if (idx < PWOFF_U32) {
        int j2   = idx & 3;
        int lane = (idx >> 2) & 63;
        int rest = idx >> 8;              // t*5 + kt
        int kt   = rest % 5;
        int t    = rest / 5;
        int comp = t / 36, r36 = t - comp * 36;
        int jw   = r36 / 9, ntg = r36 - jw * 9;
        int ochb = comp * 576 + jw * 144 + ntg * 16;
        int g    = ochb / 432;
        int ktf  = (9 * g) >> 1;
        int och  = ochb + (lane & 15);
        int ck   = (ktf + kt) * 32 + (lane >> 4) * 8 + j2 * 2 - g * 144;
        float v0 = 0.f, v1 = 0.f;
        if ((unsigned)ck < 144u)       v0 = woff[(size_t)och * 144 + ck];
        if ((unsigned)(ck + 1) < 144u) v1 = woff[(size_t)och * 144 + ck + 1];
        pw[idx] = (unsigned)bf16rne(v0) | ((unsigned)bf16rne(v1) << 16);
    } else if (idx < PWOFF_U32 + PWM_U32) {
        int m    = idx - PWOFF_U32;
        int j2   = m & 3;
        int lane = (m >> 2) & 63;
        int rest = m >> 8;                // jw*5 + pair
        int jw   = rest / 5, pair = rest - jw * 5;
        int och  = jw * 16 + (lane & 15);
        int w0   = pair * 32 + (lane >> 4) * 8 + j2 * 2;
        float v0 = (w0 < 144)     ? wmain[(size_t)och * 144 + w0]     : 0.f;
        float v1 = (w0 + 1 < 144) ? wmain[(size_t)och * 144 + w0 + 1] : 0.f;
        pw[idx] = (unsigned)bf16rne(v0) | ((unsigned)bf16rne(v1) << 16);
    }
}

__global__ __launch_bounds__(256, 2)
void deform_v6(const float* __restrict__ inps,
               const float* __restrict__ bmain,
               const float* __restrict__ boff,
               const unsigned short* __restrict__ pwoff,
               const unsigned short* __restrict__ pwm,
               float* __restrict__ out)
{
    unsigned short* IMC   = (unsigned short*)(smem + IMC6_OFF);
    unsigned short* PATCH = (unsigned short*)(smem + PATCH6_OFF);
    unsigned short* SX    = (unsigned short*)(smem + SX6_OFF);
    unsigned short* LGX   = (unsigned short*)(smem + LGX6_OFF);
    float*          OTB   = (float*)(smem + OTB6_OFF);

    const int tid  = threadIdx.x;
    const int lane = tid & 63;
    const int jw   = __builtin_amdgcn_readfirstlane(tid >> 6);
    const int slot = lane & 15;
    const int q    = lane >> 4;

    const int b    = blockIdx.x >> 7;
    const int tile = blockIdx.x & 127;
    const int ty0  = (tile >> 3) << 2;     // 16 y-tiles of 4
    const int tx0  = (tile & 7) << 3;      // 8 x-tiles of 8

    const float* inb = inps + (size_t)b * 262144;

    // ---- phase 1: PATCH bf16 [64 ch][12 y][16 x] halo 4, zero OOB ----
    for (int e = tid; e < 12288; e += 256) {
        int c = e / 192, rem = e - c * 192;
        int y = rem >> 4, x = rem & 15;
        int gy = ty0 + y - 4, gx = tx0 + x - 4;
        float v = 0.f;
        if ((unsigned)gy < 64u && (unsigned)gx < 64u)
            v = inb[(c * 64 + gy) * 64 + gx];
        PATCH[c * 198 + rem] = bf16rne(v);
    }
    __syncthreads();

    // ---- phase 2: im2col IMC[px][kk], kk = c*9 + ky*3 + kx ----
    {
        const int px  = tid >> 3;          // 0..31
        const int sub = tid & 7;
        const int pyr = px >> 3, pxx = px & 7;
        unsigned* dst = (unsigned*)(IMC + px * 584);
        #pragma unroll 4
        for (int i = 0; i < 36; ++i) {
            int kk = i * 16 + sub * 2;
            int c0 = kk / 9,        r0 = kk - c0 * 9;
            int c1 = (kk + 1) / 9,  r1 = (kk + 1) - c1 * 9;
            unsigned short a  = PATCH[c0 * 198 + (pyr + r0 / 3 + 3) * 16 + pxx + r0 % 3 + 3];
            unsigned short bb = PATCH[c1 * 198 + (pyr + r1 / 3 + 3) * 16 + pxx + r1 % 3 + 3];
            dst[(unsigned)kk >> 1] = (unsigned)a | ((unsigned)bb << 16);
        }
    }
    __syncthreads();

    f32x4 aco[2] = {{0.f,0.f,0.f,0.f},{0.f,0.f,0.f,0.f}};

    auto pair_mfma = [&](int pair) {
        const short8 bfr = ((const short8*)pwm)[(jw * 5 + pair) * 64 + lane];
        #pragma unroll
        for (int mt = 0; mt < 2; ++mt) {
            const short8 a8 = *(const short8*)(SX + jw * 1280 + (mt * 16 + slot) * 40 + q * 8);
            aco[mt] = __builtin_amdgcn_mfma_f32_16x16x32_bf16(a8, bfr, aco[mt], 0, 0, 0);
        }
    };

    // ---- phase 3: ntg loop (ONE barrier per iteration; LGX double-buffered) ----
    for (int ntg = 0; ntg < 9; ++ntg) {
        const int lb = (ntg & 1) * 2176;   // LGX buffer base (shorts)

        f32x4 aD[2] = {{0.f,0.f,0.f,0.f},{0.f,0.f,0.f,0.f}};
        f32x4 aX[2] = {{0.f,0.f,0.f,0.f},{0.f,0.f,0.f,0.f}};
        f32x4 aM[2] = {{0.f,0.f,0.f,0.f},{0.f,0.f,0.f,0.f}};

        auto gemm3 = [&](f32x4* acc, int comp) {
            const int ochb = comp * 576 + jw * 144 + ntg * 16;
            const int g    = ochb / 432;
            const int ktf  = (9 * g) >> 1;
            const int t    = comp * 36 + jw * 9 + ntg;
            const short8* wp  = (const short8*)pwoff + t * 320 + lane;   // + kt*64
            const short8* ap0 = (const short8*)(smem + IMC6_OFF);
            short8 bw[5];
            #pragma unroll
            for (int kt = 0; kt < 5; ++kt) bw[kt] = wp[kt * 64];
            #pragma unroll
            for (int kt = 0; kt < 5; ++kt) {
                const int ktg = ktf + kt;
                #pragma unroll
                for (int mt = 0; mt < 2; ++mt) {
                    const short8 af = ap0[(mt * 16 + slot) * 73 + ktg * 4 + q];
                    acc[mt] = __builtin_amdgcn_mfma_f32_16x16x32_bf16(af, bw[kt], acc[mt], 0, 0, 0);
                }
            }
            const float bo = boff[ochb + slot];
            #pragma unroll
            for (int mt = 0; mt < 2; ++mt) {
                acc[mt][0] += bo; acc[mt][1] += bo; acc[mt][2] += bo; acc[mt][3] += bo;
            }
        };
        gemm3(aD, 0); gemm3(aX, 1); gemm3(aM, 2);

        // logits -> LGX[buf][px][slot*4+j] (cross-wave)
        #pragma unroll
        for (int mt = 0; mt < 2; ++mt)
        #pragma unroll
        for (int r = 0; r < 4; ++r) {
            int pxr = mt * 16 + q * 4 + r;
            LGX[lb + pxr * 68 + slot * 4 + jw] = bf16rne(aM[mt][r]);
        }
        __syncthreads();

        // sampling (LDS patch fast path; global fallback for big offsets)
        const int rr  = ntg * 16 + slot;
        const int cg  = rr / 9;
        const int kk9 = rr - cg * 9;
        const int kyk = kk9 / 3, kxk = kk9 - kyk * 3;
        const int c   = jw * 16 + cg;
        const float* inc = inb + c * 4096;
        const int pbase = c * 198;
        const int par = ntg & 1;

        #pragma unroll
        for (int mt = 0; mt < 2; ++mt)
        #pragma unroll
        for (int r = 0; r < 4; ++r) {
            const int pxr = mt * 16 + q * 4 + r;
            const int pyr = pxr >> 3, pxx = pxr & 7;
            const float own = aM[mt][r];

            const uint2 lg = *(const uint2*)(LGX + lb + pxr * 68 + slot * 4);
            float s4 = __expf(bf16dec((unsigned short)(lg.x & 0xFFFF)) - own)
                     + __expf(bf16dec((unsigned short)(lg.x >> 16))    - own)
                     + __expf(bf16dec((unsigned short)(lg.y & 0xFFFF)) - own)
                     + __expf(bf16dec((unsigned short)(lg.y >> 16))    - own);
            const float msk = 1.0f / s4;

            float pyf = (float)(ty0 + pyr + kyk - 1) + aD[mt][r];
            float pxf = (float)(tx0 + pxx + kxk - 1) + aX[mt][r];
            float y0f = floorf(pyf), x0f = floorf(pxf);
            float wy = pyf - y0f, wx = pxf - x0f;
            int iy0 = (int)y0f, ix0 = (int)x0f;

            int ly0 = iy0 - ty0 + 4;
            int lx0 = ix0 - tx0 + 4;
            float v;
            if ((unsigned)ly0 < 11u && (unsigned)lx0 < 15u) {
                const int a = pbase + ly0 * 16 + lx0;
                float p00 = bf16dec(PATCH[a]),      p01 = bf16dec(PATCH[a + 1]);
                float p10 = bf16dec(PATCH[a + 16]), p11 = bf16dec(PATCH[a + 17]);
                float top = fmaf(wx, p01 - p00, p00);
                float bot = fmaf(wx, p11 - p10, p10);
                v = fmaf(wy, bot - top, top);
            } else {
                float w00 = (1.f - wy) * (1.f - wx), w01 = (1.f - wy) * wx;
                float w10 = wy * (1.f - wx),         w11 = wy * wx;
                v = 0.f;
                if ((unsigned)iy0 < 64u) {
                    if ((unsigned)ix0 < 64u)       v += w00 * inc[iy0 * 64 + ix0];
                    if ((unsigned)(ix0 + 1) < 64u) v += w01 * inc[iy0 * 64 + ix0 + 1];
                }
                if ((unsigned)(iy0 + 1) < 64u) {
                    if ((unsigned)ix0 < 64u)       v += w10 * inc[(iy0 + 1) * 64 + ix0];
                    if ((unsigned)(ix0 + 1) < 64u) v += w11 * inc[(iy0 + 1) * 64 + ix0 + 1];
                }
            }
            SX[jw * 1280 + pxr * 40 + par * 16 + slot] = bf16rne(v * msk);
        }

        // main-conv partial GEMM every completed pair (same-wave SX -> no barrier)
        if (ntg & 1)  { asm volatile("" ::: "memory"); pair_mfma(ntg >> 1); }
        if (ntg == 8) { asm volatile("" ::: "memory"); pair_mfma(4); }
        // no trailing barrier: LGX double-buffer removes the WAR hazard;
        // IMC/PATCH are read-only; SX is wave-private.
    }
    __syncthreads();   // all sampling reads of PATCH done before OTB overwrite

    // ---- epilogue: transpose via OTB (aliases PATCH), coalesced store ----
    {
        const int o = jw * 16 + slot;
        const float bo = bmain[o];
        #pragma unroll
        for (int mt = 0; mt < 2; ++mt)
        #pragma unroll
        for (int r = 0; r < 4; ++r)
            OTB[o * 33 + mt * 16 + q * 4 + r] = aco[mt][r] + bo;
    }
    __syncthreads();
    #pragma unroll
    for (int i = 0; i < 8; ++i) {
        int f  = i * 256 + tid;
        int oo = f >> 5, pp = f & 31;
        out[(size_t)(b * 64 + oo) * 4096 + (ty0 + (pp >> 3)) * 64 + (tx0 + (pp & 7))] =
            OTB[oo * 33 + pp];
    }
}

// ======================= v2 fallback (proven; no ws needed) =======================
#define V2IMC_OFF   0
#define V2S_OFF     37376
#define V2LGX_OFF   74752
#define V2LDS_BYTES 78848

__global__ __launch_bounds__(256, 2)
void deform_v2(const float* __restrict__ inps,
               const float* __restrict__ wmain,
               const float* __restrict__ bmain,
               const float* __restrict__ woff,
               const float* __restrict__ boff,
               float* __restrict__ out)
{
    unsigned short* IMC  = (unsigned short*)(smem + V2IMC_OFF);
    unsigned short* SBUF = (unsigned short*)(smem + V2S_OFF);
    unsigned short* LGX  = (unsigned short*)(smem + V2LGX_OFF);
    float* PATCH = (float*)(smem + V2S_OFF);
    float* OTB   = (float*)(smem + V2IMC_OFF);

    const int tid  = threadIdx.x;
    const int lane = tid & 63;
    const int jw   = __builtin_amdgcn_readfirstlane(tid >> 6);
    const int slot = lane & 15;
    const int q    = lane >> 4;

    const int b    = blockIdx.x >> 7;
    const int tile = blockIdx.x & 127;
    const int ty0  = (tile >> 3) << 2;
    const int tx0  = (tile & 7) << 3;

    const float* inb = inps + (size_t)b * 262144;

    for (int e = tid; e < 64 * 60; e += 256) {
        int ch = e / 60, rem = e - ch * 60;
        int iy = rem / 10, ix = rem - iy * 10;
        int gy = ty0 + iy - 1, gx = tx0 + ix - 1;
        float v = 0.f;
        if ((unsigned)gy < 64u && (unsigned)gx < 64u)
            v = inb[(ch * 64 + gy) * 64 + gx];
        PATCH[ch * 61 + rem] = v;
    }
    __syncthreads();
    {
        const int px  = tid >> 3;
        const int sub = tid & 7;
        const int pyr = px >> 3, pxx = px & 7;
        unsigned short* dst = IMC + px * 584;
        for (int i = 0; i < 36; ++i) {
            int kk = sub * 72 + 2 * i;
            float v0, v1;
            { int c = kk / 9, r9 = kk - c * 9, ky = r9 / 3, kx = r9 - ky * 3;
              v0 = PATCH[c * 61 + (pyr + ky) * 10 + (pxx + kx)]; }
            { int k1 = kk + 1; int c = k1 / 9, r9 = k1 - c * 9, ky = r9 / 3, kx = r9 - ky * 3;
              v1 = PATCH[c * 61 + (pyr + ky) * 10 + (pxx + kx)]; }
            *(unsigned*)(dst + kk) = cvtpk2(v0, v1);
        }
    }
    __syncthreads();

    for (int ntg = 0; ntg < 9; ++ntg) {
        f32x4 aD[2] = {{0.f,0.f,0.f,0.f},{0.f,0.f,0.f,0.f}};
        f32x4 aX[2] = {{0.f,0.f,0.f,0.f},{0.f,0.f,0.f,0.f}};
        f32x4 aM[2] = {{0.f,0.f,0.f,0.f},{0.f,0.f,0.f,0.f}};

        auto gemm3 = [&](f32x4* acc, int comp) {
            const int ochb = comp * 576 + jw * 144 + ntg * 16;
            const int g    = ochb / 432;
            const int ktf  = (9 * g) >> 1;
            const int ch0  = g * 18;
            const int och  = ochb + slot;
            #pragma unroll
            for (int kt = 0; kt < 5; ++kt) {
                const int ktg   = ktf + kt;
                const int chunk = ktg * 4 + q;
                short8 bfr;
                if ((unsigned)(chunk - ch0) < 18u) {
                    const float4* wp = (const float4*)(woff + (size_t)och * 144 + (chunk - ch0) * 8);
                    float4 w0 = wp[0], w1 = wp[1];
                    union { unsigned u[4]; short8 s; } cv;
                    cv.u[0] = cvtpk2(w0.x, w0.y); cv.u[1] = cvtpk2(w0.z, w0.w);
                    cv.u[2] = cvtpk2(w1.x, w1.y); cv.u[3] = cvtpk2(w1.z, w1.w);
                    bfr = cv.s;
                } else {
                    bfr = short8{0,0,0,0,0,0,0,0};
                }
                #pragma unroll
                for (int mt = 0; mt < 2; ++mt) {
                    const short8* ap = (const short8*)(smem + V2IMC_OFF +
                                        (mt * 16 + slot) * 1168 + ktg * 64 + q * 16);
                    acc[mt] = __builtin_amdgcn_mfma_f32_16x16x32_bf16(*ap, bfr, acc[mt], 0, 0, 0);
                }
            }
            const float bo = boff[ochb + slot];
            #pragma unroll
            for (int mt = 0; mt < 2; ++mt) {
                acc[mt][0] += bo; acc[mt][1] += bo; acc[mt][2] += bo; acc[mt][3] += bo;
            }
        };
        gemm3(aD, 0); gemm3(aX, 1); gemm3(aM, 2);

        #pragma unroll
        for (int mt = 0; mt < 2; ++mt)
        #pragma unroll
        for (int r = 0; r < 4; ++r) {
            int pxr = mt * 16 + q * 4 + r;
            LGX[(jw * 32 + pxr) * 16 + slot] = bf16rne(aM[mt][r]);
        }
        __syncthreads();

        const int rr  = ntg * 16 + slot;
        const int cg  = rr / 9;
        const int kk9 = rr - cg * 9;
        const int kyk = kk9 / 3, kxk = kk9 - kyk * 3;
        const float* inc = inb + (jw * 16 + cg) * 4096;

        #pragma unroll
        for (int mt = 0; mt < 2; ++mt)
        #pragma unroll
        for (int r = 0; r < 4; ++r) {
            const int pxr = mt * 16 + q * 4 + r;
            const int pyr = pxr >> 3, pxx = pxr & 7;
            float own = aM[mt][r];
            float l0 = (jw == 0) ? own : bf16dec(LGX[(0 * 32 + pxr) * 16 + slot]);
            float l1 = (jw == 1) ? own : bf16dec(LGX[(1 * 32 + pxr) * 16 + slot]);
            float l2 = (jw == 2) ? own : bf16dec(LGX[(2 * 32 + pxr) * 16 + slot]);
            float l3 = (jw == 3) ? own : bf16dec(LGX[(3 * 32 + pxr) * 16 + slot]);
            float m4 = fmaxf(fmaxf(l0, l1), fmaxf(l2, l3));
            float s4 = __expf(l0 - m4) + __expf(l1 - m4) + __expf(l2 - m4) + __expf(l3 - m4);
            float msk = __expf(own - m4) / s4;

            float pyf = (float)(ty0 + pyr + kyk - 1) + aD[mt][r];
            float pxf = (float)(tx0 + pxx + kxk - 1) + aX[mt][r];
            float y0f = floorf(pyf), x0f = floorf(pxf);
            float wy = pyf - y0f, wx = pxf - x0f;
            int iy0 = (int)y0f, ix0 = (int)x0f;
            float w00 = (1.f - wy) * (1.f - wx), w01 = (1.f - wy) * wx;
            float w10 = wy * (1.f - wx),         w11 = wy * wx;
            float v = 0.f;
            if ((unsigned)iy0 < 64u) {
                if ((unsigned)ix0 < 64u)       v += w00 * inc[iy0 * 64 + ix0];
                if ((unsigned)(ix0 + 1) < 64u) v += w01 * inc[iy0 * 64 + ix0 + 1];
            }
            if ((unsigned)(iy0 + 1) < 64u) {
                if ((unsigned)ix0 < 64u)       v += w10 * inc[(iy0 + 1) * 64 + ix0];
                if ((unsigned)(ix0 + 1) < 64u) v += w11 * inc[(iy0 + 1) * 64 + ix0 + 1];
            }
            SBUF[pxr * 584 + jw * 144 + rr] = bf16rne(v * msk);
        }
        __syncthreads();
    }

    {
        f32x4 aco2[2] = {{0.f,0.f,0.f,0.f},{0.f,0.f,0.f,0.f}};
        const int ktf = (9 * jw) >> 1;
        const int ch0 = jw * 18;
        const int o   = jw * 16 + slot;
        #pragma unroll
        for (int kt = 0; kt < 5; ++kt) {
            const int ktg   = ktf + kt;
            const int chunk = ktg * 4 + q;
            short8 bfr;
            if ((unsigned)(chunk - ch0) < 18u) {
                const float4* wp = (const float4*)(wmain + (size_t)o * 144 + (chunk - ch0) * 8);
                float4 w0 = wp[0], w1 = wp[1];
                union { unsigned u[4]; short8 s; } cv;
                cv.u[0] = cvtpk2(w0.x, w0.y); cv.u[1] = cvtpk2(w0.z, w0.w);
                cv.u[2] = cvtpk2(w1.x, w1.y); cv.u[3] = cvtpk2(w1.z, w1.w);
                bfr = cv.s;
            } else {
                bfr = short8{0,0,0,0,0,0,0,0};
            }
            #pragma unroll
            for (int mt = 0; mt < 2; ++mt) {
                const short8* ap = (const short8*)(smem + V2S_OFF +
                                    (mt * 16 + slot) * 1168 + ktg * 64 + q * 16);
                aco2[mt] = __builtin_amdgcn_mfma_f32_16x16x32_bf16(*ap, bfr, aco2[mt], 0, 0, 0);
            }
        }
        const float bo = bmain[o];
        __syncthreads();
        #pragma unroll
        for (int mt = 0; mt < 2; ++mt)
        #pragma unroll
        for (int r = 0; r < 4; ++r)
            OTB[o * 33 + mt * 16 + q * 4 + r] = aco2[mt][r] + bo;
    }
    __syncthreads();
    #pragma unroll
    for (int i = 0; i < 8; ++i) {
        int f  = i * 256 + tid;
        int oo = f >> 5, pp = f & 31;
        out[(size_t)(b * 64 + oo) * 4096 + (ty0 + (pp >> 3)) * 64 + (tx0 + (pp & 7))] =
            OTB[oo * 33 + pp];
    }
}

extern "C" void kernel_launch(void* const* d_in, const int* in_sizes, int n_in,
                              void* d_out, int out_size, void* d_ws, size_t ws_size,
                              hipStream_t stream) {
    const float* inps   = (const float*)d_in[0];
    const float* weight = (const float*)d_in[1];
    const float* bias   = (const float*)d_in[2];
    const float* woff   = (const float*)d_in[3];
    const float* boff   = (const float*)d_in[4];
    float* outp = (float*)d_out;

    if (ws_size >= WS_NEEDED) {
        unsigned* pw = (unsigned*)d_ws;
        pack_weights<<<dim3(560), dim3(256), 0, stream>>>(weight, woff, pw);
        hipFuncSetAttribute((const void*)deform_v6,
                            hipFuncAttributeMaxDynamicSharedMemorySize, LDS_V6);
        deform_v6<<<dim3(1024), dim3(256), LDS_V6, stream>>>(
            inps, bias, boff,
            (const unsigned short*)pw,
            (const unsigned short*)(pw + PWOFF_U32), outp);
    } else {
        hipFuncSetAttribute((const void*)deform_v2,
                            hipFuncAttributeMaxDynamicSharedMemorySize, V2LDS_BYTES);
        deform_v2<<<dim3(1024), dim3(256), V2LDS_BYTES, stream>>>(
            inps, weight, bias, woff, boff, outp);
    }
}

// Round 8
// 124.411 us; speedup vs baseline: 1.4216x; 1.0984x over previous
//
#include <hip/hip_runtime.h>

typedef __attribute__((ext_vector_type(8))) short short8;
typedef __attribute__((ext_vector_type(4))) float f32x4;

__device__ __forceinline__ unsigned short bf16rne(float f) {
    unsigned u = __float_as_uint(f);
    u += 0x7FFFu + ((u >> 16) & 1u);
    return (unsigned short)(u >> 16);
}
__device__ __forceinline__ float bf16dec(unsigned short h) {
    return __uint_as_float((unsigned)h << 16);
}
__device__ __forceinline__ unsigned cvtpk2(float lo, float hi) {
    unsigned r;
    asm("v_cvt_pk_bf16_f32 %0, %1, %2" : "=v"(r) : "v"(lo), "v"(hi));
    return r;
}

extern __shared__ char smem[];

// ============== v7: v6 dataflow, 8 waves/block (4 jw x 2 mt-halves) ==============
// 512 thr/block, LDS 81664 B -> 2 blocks/CU -> 16 waves/CU = 4 waves/SIMD (2x v6 TLP).
// Each wave owns one 16-px m-tile: gemm3 = 5 MFMA, sampling = 4 samples/lane.
// LDS map:
//   IMC   [32 px][584] bf16  @0      (37376 B)  im2col A-matrix (static addressing)
//   PATCH [64 ch][12][16]    @37376  (25344 B)  bf16 halo-4 patch, stride 198 sh
//   SX    [4 jw][32][40]     @62720  (10240 B)  sampled A-frags (wave-private halves)
//   LGX   2 x [32 px][68]    @72960  ( 8704 B)  softmax logits double-buffered
//   OTB alias @37376 (8448 B, epilogue only)

#define IMC7_OFF   0
#define PATCH7_OFF 37376
#define SX7_OFF    62720
#define LGX7_OFF   72960
#define LDS_V7     81664
#define OTB7_OFF   37376

#define LOG2E 1.4426950408889634f

#define PWOFF_U32  138240   // 108 tiles * 5 kt * 64 lanes * 4 u32 (16x16x32 B-frags)
#define PWM_U32    5120     // 4 jw * 5 pairs * 64 lanes * 4 u32
#define WS_NEEDED  ((size_t)(PWOFF_U32 + PWM_U32) * 4)

__global__ __launch_bounds__(256)
void pack_weights(const float* __restrict__ wmain,
                  const float* __restrict__ woff,
                  unsigned* __restrict__ pw)
{
    int idx = blockIdx.x * 256 + threadIdx.x;
    if (idx < PWOFF_U32) {
        int j2   = idx & 3;
        int lane = (idx >> 2) & 63;
        int rest = idx >> 8;              // t*5 + kt
        int kt   = rest % 5;
        int t    = rest / 5;
        int comp = t / 36, r36 = t - comp * 36;
        int jw   = r36 / 9, ntg = r36 - jw * 9;
        int ochb = comp * 576 + jw * 144 + ntg * 16;
        int g    = ochb / 432;
        int ktf  = (9 * g) >> 1;
        int och  = ochb + (lane & 15);
        int ck   = (ktf + kt) * 32 + (lane >> 4) * 8 + j2 * 2 - g * 144;
        float v0 = 0.f, v1 = 0.f;
        if ((unsigned)ck < 144u)       v0 = woff[(size_t)och * 144 + ck];
        if ((unsigned)(ck + 1) < 144u) v1 = woff[(size_t)och * 144 + ck + 1];
        pw[idx] = (unsigned)bf16rne(v0) | ((unsigned)bf16rne(v1) << 16);
    } else if (idx < PWOFF_U32 + PWM_U32) {
        int m    = idx - PWOFF_U32;
        int j2   = m & 3;
        int lane = (m >> 2) & 63;
        int rest = m >> 8;                // jw*5 + pair
        int jw   = rest / 5, pair = rest - jw * 5;
        int och  = jw * 16 + (lane & 15);
        int w0   = pair * 32 + (lane >> 4) * 8 + j2 * 2;
        float v0 = (w0 < 144)     ? wmain[(size_t)och * 144 + w0]     : 0.f;
        float v1 = (w0 + 1 < 144) ? wmain[(size_t)och * 144 + w0 + 1] : 0.f;
        pw[idx] = (unsigned)bf16rne(v0) | ((unsigned)bf16rne(v1) << 16);
    }
}

__global__ __launch_bounds__(512, 2)
void deform_v7(const float* __restrict__ inps,
               const float* __restrict__ bmain,
               const float* __restrict__ boff,
               const unsigned short* __restrict__ pwoff,
               const unsigned short* __restrict__ pwm,
               float* __restrict__ out)
{
    unsigned short* IMC   = (unsigned short*)(smem + IMC7_OFF);
    unsigned short* PATCH = (unsigned short*)(smem + PATCH7_OFF);
    unsigned short* SX    = (unsigned short*)(smem + SX7_OFF);
    unsigned short* LGX   = (unsigned short*)(smem + LGX7_OFF);
    float*          OTB   = (float*)(smem + OTB7_OFF);

    const int tid  = threadIdx.x;
    const int lane = tid & 63;
    const int wv   = __builtin_amdgcn_readfirstlane(tid >> 6);  // 0..7
    const int jw   = wv & 3;                                    // softmax group
    const int mtw  = wv >> 2;                                   // m-tile half
    const int slot = lane & 15;
    const int q    = lane >> 4;

    const int b    = blockIdx.x >> 7;
    const int tile = blockIdx.x & 127;
    const int ty0  = (tile >> 3) << 2;     // 16 y-tiles of 4
    const int tx0  = (tile & 7) << 3;      // 8 x-tiles of 8

    const float* inb = inps + (size_t)b * 262144;

    // ---- phase 1: PATCH bf16 [64 ch][12 y][16 x] halo 4, zero OOB ----
    for (int e = tid; e < 12288; e += 512) {
        int c = e / 192, rem = e - c * 192;
        int y = rem >> 4, x = rem & 15;
        int gy = ty0 + y - 4, gx = tx0 + x - 4;
        float v = 0.f;
        if ((unsigned)gy < 64u && (unsigned)gx < 64u)
            v = inb[(c * 64 + gy) * 64 + gx];
        PATCH[c * 198 + rem] = bf16rne(v);
    }
    __syncthreads();

    // ---- phase 2: im2col IMC[px][kk], kk = c*9 + ky*3 + kx ----
    {
        const int px  = tid >> 4;          // 0..31
        const int sub = tid & 15;          // 16 threads per px
        const int pyr = px >> 3, pxx = px & 7;
        unsigned* dst = (unsigned*)(IMC + px * 584);
        #pragma unroll 3
        for (int i = 0; i < 18; ++i) {     // 18*16 = 288 u32 = kk 0..575 exact
            int u  = i * 16 + sub;
            int kk = u * 2;
            int c0 = kk / 9,        r0 = kk - c0 * 9;
            int c1 = (kk + 1) / 9,  r1 = (kk + 1) - c1 * 9;
            unsigned short a  = PATCH[c0 * 198 + (pyr + r0 / 3 + 3) * 16 + pxx + r0 % 3 + 3];
            unsigned short bb = PATCH[c1 * 198 + (pyr + r1 / 3 + 3) * 16 + pxx + r1 % 3 + 3];
            dst[u] = (unsigned)a | ((unsigned)bb << 16);
        }
    }
    __syncthreads();

    f32x4 aco = {0.f, 0.f, 0.f, 0.f};

    auto pair_mfma = [&](int pair) {
        const short8 bfr = ((const short8*)pwm)[(jw * 5 + pair) * 64 + lane];
        const short8 a8  = *(const short8*)(SX + jw * 1280 + (mtw * 16 + slot) * 40 + q * 8);
        aco = __builtin_amdgcn_mfma_f32_16x16x32_bf16(a8, bfr, aco, 0, 0, 0);
    };

    // ---- phase 3: ntg loop (one barrier per iteration; LGX double-buffered) ----
    for (int ntg = 0; ntg < 9; ++ntg) {
        const int lb = (ntg & 1) * 2176;   // LGX buffer base (shorts)

        f32x4 aD = {0.f,0.f,0.f,0.f};
        f32x4 aX = {0.f,0.f,0.f,0.f};
        f32x4 aM = {0.f,0.f,0.f,0.f};

        auto gemm3 = [&](f32x4& acc, int comp) {
            const int ochb = comp * 576 + jw * 144 + ntg * 16;
            const int g    = ochb / 432;
            const int ktf  = (9 * g) >> 1;
            const int t    = comp * 36 + jw * 9 + ntg;
            const short8* wp  = (const short8*)pwoff + t * 320 + lane;   // + kt*64
            const short8* ap0 = (const short8*)(smem + IMC7_OFF);
            short8 bw[5];
            #pragma unroll
            for (int kt = 0; kt < 5; ++kt) bw[kt] = wp[kt * 64];
            #pragma unroll
            for (int kt = 0; kt < 5; ++kt) {
                const short8 af = ap0[(mtw * 16 + slot) * 73 + (ktf + kt) * 4 + q];
                acc = __builtin_amdgcn_mfma_f32_16x16x32_bf16(af, bw[kt], acc, 0, 0, 0);
            }
            const float bo = boff[ochb + slot];
            acc[0] += bo; acc[1] += bo; acc[2] += bo; acc[3] += bo;
        };
        gemm3(aD, 0); gemm3(aX, 1); gemm3(aM, 2);

        // scale mask logits to log2 domain (exp -> exp2)
        aM[0] *= LOG2E; aM[1] *= LOG2E; aM[2] *= LOG2E; aM[3] *= LOG2E;

        // logits -> LGX[buf][px][slot*4+j] (cross-wave)
        #pragma unroll
        for (int r = 0; r < 4; ++r) {
            int pxr = mtw * 16 + q * 4 + r;
            LGX[lb + pxr * 68 + slot * 4 + jw] = bf16rne(aM[r]);
        }
        __syncthreads();

        // sampling (LDS patch fast path; global fallback for big offsets)
        const int rr  = ntg * 16 + slot;
        const int cg  = rr / 9;
        const int kk9 = rr - cg * 9;
        const int kyk = kk9 / 3, kxk = kk9 - kyk * 3;
        const int c   = jw * 16 + cg;
        const float* inc = inb + c * 4096;
        const int pbase = c * 198;
        const int par = ntg & 1;

        #pragma unroll
        for (int r = 0; r < 4; ++r) {
            const int pxr = mtw * 16 + q * 4 + r;
            const int pyr = pxr >> 3, pxx = pxr & 7;
            const float own = aM[r];

            const uint2 lg = *(const uint2*)(LGX + lb + pxr * 68 + slot * 4);
            float s4 = exp2f(bf16dec((unsigned short)(lg.x & 0xFFFF)) - own)
                     + exp2f(bf16dec((unsigned short)(lg.x >> 16))    - own)
                     + exp2f(bf16dec((unsigned short)(lg.y & 0xFFFF)) - own)
                     + exp2f(bf16dec((unsigned short)(lg.y >> 16))    - own);
            const float msk = 1.0f / s4;

            float pyf = (float)(ty0 + pyr + kyk - 1) + aD[r];
            float pxf = (float)(tx0 + pxx + kxk - 1) + aX[r];
            float y0f = floorf(pyf), x0f = floorf(pxf);
            float wy = pyf - y0f, wx = pxf - x0f;
            int iy0 = (int)y0f, ix0 = (int)x0f;

            int ly0 = iy0 - ty0 + 4;
            int lx0 = ix0 - tx0 + 4;
            float v;
            if ((unsigned)ly0 < 11u && (unsigned)lx0 < 15u) {
                const int a = pbase + ly0 * 16 + lx0;
                float p00 = bf16dec(PATCH[a]),      p01 = bf16dec(PATCH[a + 1]);
                float p10 = bf16dec(PATCH[a + 16]), p11 = bf16dec(PATCH[a + 17]);
                float top = fmaf(wx, p01 - p00, p00);
                float bot = fmaf(wx, p11 - p10, p10);
                v = fmaf(wy, bot - top, top);
            } else {
                float w00 = (1.f - wy) * (1.f - wx), w01 = (1.f - wy) * wx;
                float w10 = wy * (1.f - wx),         w11 = wy * wx;
                v = 0.f;
                if ((unsigned)iy0 < 64u) {
                    if ((unsigned)ix0 < 64u)       v += w00 * inc[iy0 * 64 + ix0];
                    if ((unsigned)(ix0 + 1) < 64u) v += w01 * inc[iy0 * 64 + ix0 + 1];
                }
                if ((unsigned)(iy0 + 1) < 64u) {
                    if ((unsigned)ix0 < 64u)       v += w10 * inc[(iy0 + 1) * 64 + ix0];
                    if ((unsigned)(ix0 + 1) < 64u) v += w11 * inc[(iy0 + 1) * 64 + ix0 + 1];
                }
            }
            SX[jw * 1280 + pxr * 40 + par * 16 + slot] = bf16rne(v * msk);
        }

        // main-conv partial GEMM every completed pair (wave-private SX -> no barrier)
        if (ntg & 1)  { asm volatile("" ::: "memory"); pair_mfma(ntg >> 1); }
        if (ntg == 8) { asm volatile("" ::: "memory"); pair_mfma(4); }
        // no trailing barrier: LGX double-buffer removes the WAR hazard;
        // IMC/PATCH read-only; SX wave-private per (jw, mtw).
    }
    __syncthreads();   // all sampling reads of PATCH done before OTB overwrite

    // ---- epilogue: transpose via OTB (aliases PATCH), coalesced store ----
    {
        const int o = jw * 16 + slot;
        const float bo = bmain[o];
        #pragma unroll
        for (int r = 0; r < 4; ++r)
            OTB[o * 33 + mtw * 16 + q * 4 + r] = aco[r] + bo;
    }
    __syncthreads();
    #pragma unroll
    for (int i = 0; i < 4; ++i) {
        int f  = i * 512 + tid;
        int oo = f >> 5, pp = f & 31;
        out[(size_t)(b * 64 + oo) * 4096 + (ty0 + (pp >> 3)) * 64 + (tx0 + (pp & 7))] =
            OTB[oo * 33 + pp];
    }
}

// ======================= v2 fallback (proven; no ws needed) =======================
#define V2IMC_OFF   0
#define V2S_OFF     37376
#define V2LGX_OFF   74752
#define V2LDS_BYTES 78848

__global__ __launch_bounds__(256, 2)
void deform_v2(const float* __restrict__ inps,
               const float* __restrict__ wmain,
               const float* __restrict__ bmain,
               const float* __restrict__ woff,
               const float* __restrict__ boff,
               float* __restrict__ out)
{
    unsigned short* IMC  = (unsigned short*)(smem + V2IMC_OFF);
    unsigned short* SBUF = (unsigned short*)(smem + V2S_OFF);
    unsigned short* LGX  = (unsigned short*)(smem + V2LGX_OFF);
    float* PATCH = (float*)(smem + V2S_OFF);
    float* OTB   = (float*)(smem + V2IMC_OFF);

    const int tid  = threadIdx.x;
    const int lane = tid & 63;
    const int jw   = __builtin_amdgcn_readfirstlane(tid >> 6);
    const int slot = lane & 15;
    const int q    = lane >> 4;

    const int b    = blockIdx.x >> 7;
    const int tile = blockIdx.x & 127;
    const int ty0  = (tile >> 3) << 2;
    const int tx0  = (tile & 7) << 3;

    const float* inb = inps + (size_t)b * 262144;

    for (int e = tid; e < 64 * 60; e += 256) {
        int ch = e / 60, rem = e - ch * 60;
        int iy = rem / 10, ix = rem - iy * 10;
        int gy = ty0 + iy - 1, gx = tx0 + ix - 1;
        float v = 0.f;
        if ((unsigned)gy < 64u && (unsigned)gx < 64u)
            v = inb[(ch * 64 + gy) * 64 + gx];
        PATCH[ch * 61 + rem] = v;
    }
    __syncthreads();
    {
        const int px  = tid >> 3;
        const int sub = tid & 7;
        const int pyr = px >> 3, pxx = px & 7;
        unsigned short* dst = IMC + px * 584;
        for (int i = 0; i < 36; ++i) {
            int kk = sub * 72 + 2 * i;
            float v0, v1;
            { int c = kk / 9, r9 = kk - c * 9, ky = r9 / 3, kx = r9 - ky * 3;
              v0 = PATCH[c * 61 + (pyr + ky) * 10 + (pxx + kx)]; }
            { int k1 = kk + 1; int c = k1 / 9, r9 = k1 - c * 9, ky = r9 / 3, kx = r9 - ky * 3;
              v1 = PATCH[c * 61 + (pyr + ky) * 10 + (pxx + kx)]; }
            *(unsigned*)(dst + kk) = cvtpk2(v0, v1);
        }
    }
    __syncthreads();

    for (int ntg = 0; ntg < 9; ++ntg) {
        f32x4 aD[2] = {{0.f,0.f,0.f,0.f},{0.f,0.f,0.f,0.f}};
        f32x4 aX[2] = {{0.f,0.f,0.f,0.f},{0.f,0.f,0.f,0.f}};
        f32x4 aM[2] = {{0.f,0.f,0.f,0.f},{0.f,0.f,0.f,0.f}};

        auto gemm3 = [&](f32x4* acc, int comp) {
            const int ochb = comp * 576 + jw * 144 + ntg * 16;
            const int g    = ochb / 432;
            const int ktf  = (9 * g) >> 1;
            const int ch0  = g * 18;
            const int och  = ochb + slot;
            #pragma unroll
            for (int kt = 0; kt < 5; ++kt) {
                const int ktg   = ktf + kt;
                const int chunk = ktg * 4 + q;
                short8 bfr;
                if ((unsigned)(chunk - ch0) < 18u) {
                    const float4* wp = (const float4*)(woff + (size_t)och * 144 + (chunk - ch0) * 8);
                    float4 w0 = wp[0], w1 = wp[1];
                    union { unsigned u[4]; short8 s; } cv;
                    cv.u[0] = cvtpk2(w0.x, w0.y); cv.u[1] = cvtpk2(w0.z, w0.w);
                    cv.u[2] = cvtpk2(w1.x, w1.y); cv.u[3] = cvtpk2(w1.z, w1.w);
                    bfr = cv.s;
                } else {
                    bfr = short8{0,0,0,0,0,0,0,0};
                }
                #pragma unroll
                for (int mt = 0; mt < 2; ++mt) {
                    const short8* ap = (const short8*)(smem + V2IMC_OFF +
                                        (mt * 16 + slot) * 1168 + ktg * 64 + q * 16);
                    acc[mt] = __builtin_amdgcn_mfma_f32_16x16x32_bf16(*ap, bfr, acc[mt], 0, 0, 0);
                }
            }
            const float bo = boff[ochb + slot];
            #pragma unroll
            for (int mt = 0; mt < 2; ++mt) {
                acc[mt][0] += bo; acc[mt][1] += bo; acc[mt][2] += bo; acc[mt][3] += bo;
            }
        };
        gemm3(aD, 0); gemm3(aX, 1); gemm3(aM, 2);

        #pragma unroll
        for (int mt = 0; mt < 2; ++mt)
        #pragma unroll
        for (int r = 0; r < 4; ++r) {
            int pxr = mt * 16 + q * 4 + r;
            LGX[(jw * 32 + pxr) * 16 + slot] = bf16rne(aM[mt][r]);
        }
        __syncthreads();

        const int rr  = ntg * 16 + slot;
        const int cg  = rr / 9;
        const int kk9 = rr - cg * 9;
        const int kyk = kk9 / 3, kxk = kk9 - kyk * 3;
        const float* inc = inb + (jw * 16 + cg) * 4096;

        #pragma unroll
        for (int mt = 0; mt < 2; ++mt)
        #pragma unroll
        for (int r = 0; r < 4; ++r) {
            const int pxr = mt * 16 + q * 4 + r;
            const int pyr = pxr >> 3, pxx = pxr & 7;
            float own = aM[mt][r];
            float l0 = (jw == 0) ? own : bf16dec(LGX[(0 * 32 + pxr) * 16 + slot]);
            float l1 = (jw == 1) ? own : bf16dec(LGX[(1 * 32 + pxr) * 16 + slot]);
            float l2 = (jw == 2) ? own : bf16dec(LGX[(2 * 32 + pxr) * 16 + slot]);
            float l3 = (jw == 3) ? own : bf16dec(LGX[(3 * 32 + pxr) * 16 + slot]);
            float m4 = fmaxf(fmaxf(l0, l1), fmaxf(l2, l3));
            float s4 = __expf(l0 - m4) + __expf(l1 - m4) + __expf(l2 - m4) + __expf(l3 - m4);
            float msk = __expf(own - m4) / s4;

            float pyf = (float)(ty0 + pyr + kyk - 1) + aD[mt][r];
            float pxf = (float)(tx0 + pxx + kxk - 1) + aX[mt][r];
            float y0f = floorf(pyf), x0f = floorf(pxf);
            float wy = pyf - y0f, wx = pxf - x0f;
            int iy0 = (int)y0f, ix0 = (int)x0f;
            float w00 = (1.f - wy) * (1.f - wx), w01 = (1.f - wy) * wx;
            float w10 = wy * (1.f - wx),         w11 = wy * wx;
            float v = 0.f;
            if ((unsigned)iy0 < 64u) {
                if ((unsigned)ix0 < 64u)       v += w00 * inc[iy0 * 64 + ix0];
                if ((unsigned)(ix0 + 1) < 64u) v += w01 * inc[iy0 * 64 + ix0 + 1];
            }
            if ((unsigned)(iy0 + 1) < 64u) {
                if ((unsigned)ix0 < 64u)       v += w10 * inc[(iy0 + 1) * 64 + ix0];
                if ((unsigned)(ix0 + 1) < 64u) v += w11 * inc[(iy0 + 1) * 64 + ix0 + 1];
            }
            SBUF[pxr * 584 + jw * 144 + rr] = bf16rne(v * msk);
        }
        __syncthreads();
    }

    {
        f32x4 aco2[2] = {{0.f,0.f,0.f,0.f},{0.f,0.f,0.f,0.f}};
        const int ktf = (9 * jw) >> 1;
        const int ch0 = jw * 18;
        const int o   = jw * 16 + slot;
        #pragma unroll
        for (int kt = 0; kt < 5; ++kt) {
            const int ktg   = ktf + kt;
            const int chunk = ktg * 4 + q;
            short8 bfr;
            if ((unsigned)(chunk - ch0) < 18u) {
                const float4* wp = (const float4*)(wmain + (size_t)o * 144 + (chunk - ch0) * 8);
                float4 w0 = wp[0], w1 = wp[1];
                union { unsigned u[4]; short8 s; } cv;
                cv.u[0] = cvtpk2(w0.x, w0.y); cv.u[1] = cvtpk2(w0.z, w0.w);
                cv.u[2] = cvtpk2(w1.x, w1.y); cv.u[3] = cvtpk2(w1.z, w1.w);
                bfr = cv.s;
            } else {
                bfr = short8{0,0,0,0,0,0,0,0};
            }
            #pragma unroll
            for (int mt = 0; mt < 2; ++mt) {
                const short8* ap = (const short8*)(smem + V2S_OFF +
                                    (mt * 16 + slot) * 1168 + ktg * 64 + q * 16);
                aco2[mt] = __builtin_amdgcn_mfma_f32_16x16x32_bf16(*ap, bfr, aco2[mt], 0, 0, 0);
            }
        }
        const float bo = bmain[o];
        __syncthreads();
        #pragma unroll
        for (int mt = 0; mt < 2; ++mt)
        #pragma unroll
        for (int r = 0; r < 4; ++r)
            OTB[o * 33 + mt * 16 + q * 4 + r] = aco2[mt][r] + bo;
    }
    __syncthreads();
    #pragma unroll
    for (int i = 0; i < 8; ++i) {
        int f  = i * 256 + tid;
        int oo = f >> 5, pp = f & 31;
        out[(size_t)(b * 64 + oo) * 4096 + (ty0 + (pp >> 3)) * 64 + (tx0 + (pp & 7))] =
            OTB[oo * 33 + pp];
    }
}

extern "C" void kernel_launch(void* const* d_in, const int* in_sizes, int n_in,
                              void* d_out, int out_size, void* d_ws, size_t ws_size,
                              hipStream_t stream) {
    const float* inps   = (const float*)d_in[0];
    const float* weight = (const float*)d_in[1];
    const float* bias   = (const float*)d_in[2];
    const float* woff   = (const float*)d_in[3];
    const float* boff   = (const float*)d_in[4];
    float* outp = (float*)d_out;

    if (ws_size >= WS_NEEDED) {
        unsigned* pw = (unsigned*)d_ws;
        pack_weights<<<dim3(560), dim3(256), 0, stream>>>(weight, woff, pw);
        hipFuncSetAttribute((const void*)deform_v7,
                            hipFuncAttributeMaxDynamicSharedMemorySize, LDS_V7);
        deform_v7<<<dim3(1024), dim3(512), LDS_V7, stream>>>(
            inps, bias, boff,
            (const unsigned short*)pw,
            (const unsigned short*)(pw + PWOFF_U32), outp);
    } else {
        hipFuncSetAttribute((const void*)deform_v2,
                            hipFuncAttributeMaxDynamicSharedMemorySize, V2LDS_BYTES);
        deform_v2<<<dim3(1024), dim3(256), V2LDS_BYTES, stream>>>(
            inps, weight, bias, woff, boff, outp);
    }
}

// Round 9
// 123.680 us; speedup vs baseline: 1.4300x; 1.0059x over previous
//
#include <hip/hip_runtime.h>

typedef __attribute__((ext_vector_type(8))) short short8;
typedef __attribute__((ext_vector_type(4))) float f32x4;

__device__ __forceinline__ unsigned short bf16rne(float f) {
    unsigned u = __float_as_uint(f);
    u += 0x7FFFu + ((u >> 16) & 1u);
    return (unsigned short)(u >> 16);
}
__device__ __forceinline__ float bf16dec(unsigned short h) {
    return __uint_as_float((unsigned)h << 16);
}
__device__ __forceinline__ unsigned cvtpk2(float lo, float hi) {
    unsigned r;
    asm("v_cvt_pk_bf16_f32 %0, %1, %2" : "=v"(r) : "v"(lo), "v"(hi));
    return r;
}
__device__ __forceinline__ unsigned short cvt1(float f) {   // 1-op f32->bf16 (RNE)
    return (unsigned short)cvtpk2(f, f);
}
__device__ __forceinline__ float declo(unsigned u) { return __uint_as_float(u << 16); }
__device__ __forceinline__ float dechi(unsigned u) { return __uint_as_float(u & 0xFFFF0000u); }

extern __shared__ char smem[];

// ============== v8: v7 + shared softmax exps + cvt_pk + B-frag prefetch ==============
// 512 thr/block (4 jw x 2 mt halves), LDS 81664 B -> 2 blocks/CU = 4 waves/SIMD.
// LGX now stores exp2(logit) in bf16 (each wave exponentiates only its own 4
// logits; consumers just sum 4 decoded exps). All hot f32->bf16 via v_cvt_pk.
// LDS map:
//   IMC   [32 px][584] bf16  @0      (37376 B)  im2col A-matrix
//   PATCH [64 ch][12][16]    @37376  (25344 B)  bf16 halo-4 patch, stride 198 sh
//   SX    [4 jw][32][40]     @62720  (10240 B)  sampled A-frags (wave-private)
//   LGX   2 x [32 px][68]    @72960  ( 8704 B)  softmax EXPS double-buffered
//   OTB alias @37376 (8448 B, epilogue only)

#define IMC8_OFF   0
#define PATCH8_OFF 37376
#define SX8_OFF    62720
#define LGX8_OFF   72960
#define LDS_V8     81664
#define OTB8_OFF   37376

#define LOG2E 1.4426950408889634f

#define PWOFF_U32  138240
#define PWM_U32    5120
#define WS_NEEDED  ((size_t)(PWOFF_U32 + PWM_U32) * 4)

__global__ __launch_bounds__(256)
void pack_weights(const float* __restrict__ wmain,
                  const float* __restrict__ woff,
                  unsigned* __restrict__ pw)
{
    int idx = blockIdx.x * 256 + threadIdx.x;
    if (idx < PWOFF_U32) {
        int j2   = idx & 3;
        int lane = (idx >> 2) & 63;
        int rest = idx >> 8;              // t*5 + kt
        int kt   = rest % 5;
        int t    = rest / 5;
        int comp = t / 36, r36 = t - comp * 36;
        int jw   = r36 / 9, ntg = r36 - jw * 9;
        int ochb = comp * 576 + jw * 144 + ntg * 16;
        int g    = ochb / 432;
        int ktf  = (9 * g) >> 1;
        int och  = ochb + (lane & 15);
        int ck   = (ktf + kt) * 32 + (lane >> 4) * 8 + j2 * 2 - g * 144;
        float v0 = 0.f, v1 = 0.f;
        if ((unsigned)ck < 144u)       v0 = woff[(size_t)och * 144 + ck];
        if ((unsigned)(ck + 1) < 144u) v1 = woff[(size_t)och * 144 + ck + 1];
        pw[idx] = (unsigned)bf16rne(v0) | ((unsigned)bf16rne(v1) << 16);
    } else if (idx < PWOFF_U32 + PWM_U32) {
        int m    = idx - PWOFF_U32;
        int j2   = m & 3;
        int lane = (m >> 2) & 63;
        int rest = m >> 8;                // jw*5 + pair
        int jw   = rest / 5, pair = rest - jw * 5;
        int och  = jw * 16 + (lane & 15);
        int w0   = pair * 32 + (lane >> 4) * 8 + j2 * 2;
        float v0 = (w0 < 144)     ? wmain[(size_t)och * 144 + w0]     : 0.f;
        float v1 = (w0 + 1 < 144) ? wmain[(size_t)och * 144 + w0 + 1] : 0.f;
        pw[idx] = (unsigned)bf16rne(v0) | ((unsigned)bf16rne(v1) << 16);
    }
}

__global__ __launch_bounds__(512, 4)
void deform_v8(const float* __restrict__ inps,
               const float* __restrict__ bmain,
               const float* __restrict__ boff,
               const unsigned short* __restrict__ pwoff,
               const unsigned short* __restrict__ pwm,
               float* __restrict__ out)
{
    unsigned short* IMC   = (unsigned short*)(smem + IMC8_OFF);
    unsigned short* PATCH = (unsigned short*)(smem + PATCH8_OFF);
    unsigned short* SX    = (unsigned short*)(smem + SX8_OFF);
    unsigned short* LGX   = (unsigned short*)(smem + LGX8_OFF);
    float*          OTB   = (float*)(smem + OTB8_OFF);

    const int tid  = threadIdx.x;
    const int lane = tid & 63;
    const int wv   = __builtin_amdgcn_readfirstlane(tid >> 6);  // 0..7
    const int jw   = wv & 3;                                    // softmax group
    const int mtw  = wv >> 2;                                   // m-tile half
    const int slot = lane & 15;
    const int q    = lane >> 4;

    const int b    = blockIdx.x >> 7;
    const int tile = blockIdx.x & 127;
    const int ty0  = (tile >> 3) << 2;     // 16 y-tiles of 4
    const int tx0  = (tile & 7) << 3;      // 8 x-tiles of 8

    const float* inb = inps + (size_t)b * 262144;

    // ---- phase 1: PATCH bf16 [64 ch][12 y][16 x] halo 4, zero OOB ----
    for (int e = tid; e < 12288; e += 512) {
        int c = e / 192, rem = e - c * 192;
        int y = rem >> 4, x = rem & 15;
        int gy = ty0 + y - 4, gx = tx0 + x - 4;
        float v = 0.f;
        if ((unsigned)gy < 64u && (unsigned)gx < 64u)
            v = inb[(c * 64 + gy) * 64 + gx];
        PATCH[c * 198 + rem] = cvt1(v);
    }
    __syncthreads();

    // ---- phase 2: im2col IMC[px][kk], kk = c*9 + ky*3 + kx ----
    {
        const int px  = tid >> 4;          // 0..31
        const int sub = tid & 15;          // 16 threads per px
        const int pyr = px >> 3, pxx = px & 7;
        unsigned* dst = (unsigned*)(IMC + px * 584);
        #pragma unroll 3
        for (int i = 0; i < 18; ++i) {     // 18*16 = 288 u32 = kk 0..575
            int u  = i * 16 + sub;
            int kk = u * 2;
            int c0 = kk / 9,        r0 = kk - c0 * 9;
            int c1 = (kk + 1) / 9,  r1 = (kk + 1) - c1 * 9;
            unsigned short a  = PATCH[c0 * 198 + (pyr + r0 / 3 + 3) * 16 + pxx + r0 % 3 + 3];
            unsigned short bb = PATCH[c1 * 198 + (pyr + r1 / 3 + 3) * 16 + pxx + r1 % 3 + 3];
            dst[u] = (unsigned)a | ((unsigned)bb << 16);
        }
    }
    __syncthreads();

    f32x4 aco = {0.f, 0.f, 0.f, 0.f};

    auto pair_mfma = [&](int pair) {
        const short8 bfr = ((const short8*)pwm)[(jw * 5 + pair) * 64 + lane];
        const short8 a8  = *(const short8*)(SX + jw * 1280 + (mtw * 16 + slot) * 40 + q * 8);
        aco = __builtin_amdgcn_mfma_f32_16x16x32_bf16(a8, bfr, aco, 0, 0, 0);
    };

    // ---- phase 3: ntg loop (one barrier per iteration; LGX double-buffered) ----
    for (int ntg = 0; ntg < 9; ++ntg) {
        const int lb = (ntg & 1) * 2176;   // LGX buffer base (shorts)

        // prefetch all 15 B-fragments for this ntg (batched vmcnt)
        short8 bwA[15];
        #pragma unroll
        for (int comp = 0; comp < 3; ++comp) {
            const short8* wp = (const short8*)pwoff + (comp * 36 + jw * 9 + ntg) * 320 + lane;
            #pragma unroll
            for (int kt = 0; kt < 5; ++kt) bwA[comp * 5 + kt] = wp[kt * 64];
        }

        f32x4 aD = {0.f,0.f,0.f,0.f};
        f32x4 aX = {0.f,0.f,0.f,0.f};
        f32x4 aM = {0.f,0.f,0.f,0.f};

        auto gemm3 = [&](f32x4& acc, int comp) {
            const int ochb = comp * 576 + jw * 144 + ntg * 16;
            const int g    = ochb / 432;
            const int ktf  = (9 * g) >> 1;
            const short8* ap0 = (const short8*)(smem + IMC8_OFF);
            #pragma unroll
            for (int kt = 0; kt < 5; ++kt) {
                const short8 af = ap0[(mtw * 16 + slot) * 73 + (ktf + kt) * 4 + q];
                acc = __builtin_amdgcn_mfma_f32_16x16x32_bf16(af, bwA[comp * 5 + kt], acc, 0, 0, 0);
            }
            const float bo = boff[ochb + slot];
            acc[0] += bo; acc[1] += bo; acc[2] += bo; acc[3] += bo;
        };
        gemm3(aD, 0); gemm3(aX, 1); gemm3(aM, 2);

        // own exps (log2 domain), keep f32 copies; write bf16 exps to LGX
        float er[4];
        #pragma unroll
        for (int r = 0; r < 4; ++r) {
            er[r] = exp2f(aM[r] * LOG2E);
            int pxr = mtw * 16 + q * 4 + r;
            LGX[lb + pxr * 68 + slot * 4 + jw] = cvt1(er[r]);
        }
        __syncthreads();

        // sampling (LDS patch fast path; global fallback for big offsets)
        const int rr  = ntg * 16 + slot;
        const int cg  = rr / 9;
        const int kk9 = rr - cg * 9;
        const int kyk = kk9 / 3, kxk = kk9 - kyk * 3;
        const int c   = jw * 16 + cg;
        const float* inc = inb + c * 4096;
        const int pbase = c * 198;
        const int par = ntg & 1;
        const float fyk = (float)(ty0 + kyk - 1);   // + pyr + dy = sample y
        const float fxk = (float)(tx0 + kxk - 1);

        #pragma unroll
        for (int r = 0; r < 4; ++r) {
            const int pxr = mtw * 16 + q * 4 + r;
            const int pyr = pxr >> 3, pxx = pxr & 7;

            const uint2 lg = *(const uint2*)(LGX + lb + pxr * 68 + slot * 4);
            const float s4 = declo(lg.x) + dechi(lg.x) + declo(lg.y) + dechi(lg.y);
            const float msk = er[r] / s4;

            float pyf = fyk + (float)pyr + aD[r];
            float pxf = fxk + (float)pxx + aX[r];
            float y0f = floorf(pyf), x0f = floorf(pxf);
            float wy = pyf - y0f, wx = pxf - x0f;
            int iy0 = (int)y0f, ix0 = (int)x0f;

            int ly0 = iy0 - ty0 + 4;
            int lx0 = ix0 - tx0 + 4;
            float v;
            if ((unsigned)ly0 < 11u && (unsigned)lx0 < 15u) {
                const int a = pbase + ly0 * 16 + lx0;
                float p00 = bf16dec(PATCH[a]),      p01 = bf16dec(PATCH[a + 1]);
                float p10 = bf16dec(PATCH[a + 16]), p11 = bf16dec(PATCH[a + 17]);
                float top = fmaf(wx, p01 - p00, p00);
                float bot = fmaf(wx, p11 - p10, p10);
                v = fmaf(wy, bot - top, top);
            } else {
                float w00 = (1.f - wy) * (1.f - wx), w01 = (1.f - wy) * wx;
                float w10 = wy * (1.f - wx),         w11 = wy * wx;
                v = 0.f;
                if ((unsigned)iy0 < 64u) {
                    if ((unsigned)ix0 < 64u)       v += w00 * inc[iy0 * 64 + ix0];
                    if ((unsigned)(ix0 + 1) < 64u) v += w01 * inc[iy0 * 64 + ix0 + 1];
                }
                if ((unsigned)(iy0 + 1) < 64u) {
                    if ((unsigned)ix0 < 64u)       v += w10 * inc[(iy0 + 1) * 64 + ix0];
                    if ((unsigned)(ix0 + 1) < 64u) v += w11 * inc[(iy0 + 1) * 64 + ix0 + 1];
                }
            }
            SX[jw * 1280 + pxr * 40 + par * 16 + slot] = cvt1(v * msk);
        }

        // main-conv partial GEMM every completed pair (wave-private SX -> no barrier)
        if (ntg & 1)  { asm volatile("" ::: "memory"); pair_mfma(ntg >> 1); }
        if (ntg == 8) { asm volatile("" ::: "memory"); pair_mfma(4); }
        // no trailing barrier: LGX double-buffer removes the WAR hazard;
        // IMC/PATCH read-only; SX wave-private per (jw, mtw).
    }
    __syncthreads();   // all sampling reads of PATCH done before OTB overwrite

    // ---- epilogue: transpose via OTB (aliases PATCH), coalesced store ----
    {
        const int o = jw * 16 + slot;
        const float bo = bmain[o];
        #pragma unroll
        for (int r = 0; r < 4; ++r)
            OTB[o * 33 + mtw * 16 + q * 4 + r] = aco[r] + bo;
    }
    __syncthreads();
    #pragma unroll
    for (int i = 0; i < 4; ++i) {
        int f  = i * 512 + tid;
        int oo = f >> 5, pp = f & 31;
        out[(size_t)(b * 64 + oo) * 4096 + (ty0 + (pp >> 3)) * 64 + (tx0 + (pp & 7))] =
            OTB[oo * 33 + pp];
    }
}

// ======================= v2 fallback (proven; no ws needed) =======================
#define V2IMC_OFF   0
#define V2S_OFF     37376
#define V2LGX_OFF   74752
#define V2LDS_BYTES 78848

__global__ __launch_bounds__(256, 2)
void deform_v2(const float* __restrict__ inps,
               const float* __restrict__ wmain,
               const float* __restrict__ bmain,
               const float* __restrict__ woff,
               const float* __restrict__ boff,
               float* __restrict__ out)
{
    unsigned short* IMC  = (unsigned short*)(smem + V2IMC_OFF);
    unsigned short* SBUF = (unsigned short*)(smem + V2S_OFF);
    unsigned short* LGX  = (unsigned short*)(smem + V2LGX_OFF);
    float* PATCH = (float*)(smem + V2S_OFF);
    float* OTB   = (float*)(smem + V2IMC_OFF);

    const int tid  = threadIdx.x;
    const int lane = tid & 63;
    const int jw   = __builtin_amdgcn_readfirstlane(tid >> 6);
    const int slot = lane & 15;
    const int q    = lane >> 4;

    const int b    = blockIdx.x >> 7;
    const int tile = blockIdx.x & 127;
    const int ty0  = (tile >> 3) << 2;
    const int tx0  = (tile & 7) << 3;

    const float* inb = inps + (size_t)b * 262144;

    for (int e = tid; e < 64 * 60; e += 256) {
        int ch = e / 60, rem = e - ch * 60;
        int iy = rem / 10, ix = rem - iy * 10;
        int gy = ty0 + iy - 1, gx = tx0 + ix - 1;
        float v = 0.f;
        if ((unsigned)gy < 64u && (unsigned)gx < 64u)
            v = inb[(ch * 64 + gy) * 64 + gx];
        PATCH[ch * 61 + rem] = v;
    }
    __syncthreads();
    {
        const int px  = tid >> 3;
        const int sub = tid & 7;
        const int pyr = px >> 3, pxx = px & 7;
        unsigned short* dst = IMC + px * 584;
        for (int i = 0; i < 36; ++i) {
            int kk = sub * 72 + 2 * i;
            float v0, v1;
            { int c = kk / 9, r9 = kk - c * 9, ky = r9 / 3, kx = r9 - ky * 3;
              v0 = PATCH[c * 61 + (pyr + ky) * 10 + (pxx + kx)]; }
            { int k1 = kk + 1; int c = k1 / 9, r9 = k1 - c * 9, ky = r9 / 3, kx = r9 - ky * 3;
              v1 = PATCH[c * 61 + (pyr + ky) * 10 + (pxx + kx)]; }
            *(unsigned*)(dst + kk) = cvtpk2(v0, v1);
        }
    }
    __syncthreads();

    for (int ntg = 0; ntg < 9; ++ntg) {
        f32x4 aD[2] = {{0.f,0.f,0.f,0.f},{0.f,0.f,0.f,0.f}};
        f32x4 aX[2] = {{0.f,0.f,0.f,0.f},{0.f,0.f,0.f,0.f}};
        f32x4 aM[2] = {{0.f,0.f,0.f,0.f},{0.f,0.f,0.f,0.f}};

        auto gemm3 = [&](f32x4* acc, int comp) {
            const int ochb = comp * 576 + jw * 144 + ntg * 16;
            const int g    = ochb / 432;
            const int ktf  = (9 * g) >> 1;
            const int ch0  = g * 18;
            const int och  = ochb + slot;
            #pragma unroll
            for (int kt = 0; kt < 5; ++kt) {
                const int ktg   = ktf + kt;
                const int chunk = ktg * 4 + q;
                short8 bfr;
                if ((unsigned)(chunk - ch0) < 18u) {
                    const float4* wp = (const float4*)(woff + (size_t)och * 144 + (chunk - ch0) * 8);
                    float4 w0 = wp[0], w1 = wp[1];
                    union { unsigned u[4]; short8 s; } cv;
                    cv.u[0] = cvtpk2(w0.x, w0.y); cv.u[1] = cvtpk2(w0.z, w0.w);
                    cv.u[2] = cvtpk2(w1.x, w1.y); cv.u[3] = cvtpk2(w1.z, w1.w);
                    bfr = cv.s;
                } else {
                    bfr = short8{0,0,0,0,0,0,0,0};
                }
                #pragma unroll
                for (int mt = 0; mt < 2; ++mt) {
                    const short8* ap = (const short8*)(smem + V2IMC_OFF +
                                        (mt * 16 + slot) * 1168 + ktg * 64 + q * 16);
                    acc[mt] = __builtin_amdgcn_mfma_f32_16x16x32_bf16(*ap, bfr, acc[mt], 0, 0, 0);
                }
            }
            const float bo = boff[ochb + slot];
            #pragma unroll
            for (int mt = 0; mt < 2; ++mt) {
                acc[mt][0] += bo; acc[mt][1] += bo; acc[mt][2] += bo; acc[mt][3] += bo;
            }
        };
        gemm3(aD, 0); gemm3(aX, 1); gemm3(aM, 2);

        #pragma unroll
        for (int mt = 0; mt < 2; ++mt)
        #pragma unroll
        for (int r = 0; r < 4; ++r) {
            int pxr = mt * 16 + q * 4 + r;
            LGX[(jw * 32 + pxr) * 16 + slot] = bf16rne(aM[mt][r]);
        }
        __syncthreads();

        const int rr  = ntg * 16 + slot;
        const int cg  = rr / 9;
        const int kk9 = rr - cg * 9;
        const int kyk = kk9 / 3, kxk = kk9 - kyk * 3;
        const float* inc = inb + (jw * 16 + cg) * 4096;

        #pragma unroll
        for (int mt = 0; mt < 2; ++mt)
        #pragma unroll
        for (int r = 0; r < 4; ++r) {
            const int pxr = mt * 16 + q * 4 + r;
            const int pyr = pxr >> 3, pxx = pxr & 7;
            float own = aM[mt][r];
            float l0 = (jw == 0) ? own : bf16dec(LGX[(0 * 32 + pxr) * 16 + slot]);
            float l1 = (jw == 1) ? own : bf16dec(LGX[(1 * 32 + pxr) * 16 + slot]);
            float l2 = (jw == 2) ? own : bf16dec(LGX[(2 * 32 + pxr) * 16 + slot]);
            float l3 = (jw == 3) ? own : bf16dec(LGX[(3 * 32 + pxr) * 16 + slot]);
            float m4 = fmaxf(fmaxf(l0, l1), fmaxf(l2, l3));
            float s4 = __expf(l0 - m4) + __expf(l1 - m4) + __expf(l2 - m4) + __expf(l3 - m4);
            float msk = __expf(own - m4) / s4;

            float pyf = (float)(ty0 + pyr + kyk - 1) + aD[mt][r];
            float pxf = (float)(tx0 + pxx + kxk - 1) + aX[mt][r];
            float y0f = floorf(pyf), x0f = floorf(pxf);
            float wy = pyf - y0f, wx = pxf - x0f;
            int iy0 = (int)y0f, ix0 = (int)x0f;
            float w00 = (1.f - wy) * (1.f - wx), w01 = (1.f - wy) * wx;
            float w10 = wy * (1.f - wx),         w11 = wy * wx;
            float v = 0.f;
            if ((unsigned)iy0 < 64u) {
                if ((unsigned)ix0 < 64u)       v += w00 * inc[iy0 * 64 + ix0];
                if ((unsigned)(ix0 + 1) < 64u) v += w01 * inc[iy0 * 64 + ix0 + 1];
            }
            if ((unsigned)(iy0 + 1) < 64u) {
                if ((unsigned)ix0 < 64u)       v += w10 * inc[(iy0 + 1) * 64 + ix0];
                if ((unsigned)(ix0 + 1) < 64u) v += w11 * inc[(iy0 + 1) * 64 + ix0 + 1];
            }
            SBUF[pxr * 584 + jw * 144 + rr] = bf16rne(v * msk);
        }
        __syncthreads();
    }

    {
        f32x4 aco2[2] = {{0.f,0.f,0.f,0.f},{0.f,0.f,0.f,0.f}};
        const int ktf = (9 * jw) >> 1;
        const int ch0 = jw * 18;
        const int o   = jw * 16 + slot;
        #pragma unroll
        for (int kt = 0; kt < 5; ++kt) {
            const int ktg   = ktf + kt;
            const int chunk = ktg * 4 + q;
            short8 bfr;
            if ((unsigned)(chunk - ch0) < 18u) {
                const float4* wp = (const float4*)(wmain + (size_t)o * 144 + (chunk - ch0) * 8);
                float4 w0 = wp[0], w1 = wp[1];
                union { unsigned u[4]; short8 s; } cv;
                cv.u[0] = cvtpk2(w0.x, w0.y); cv.u[1] = cvtpk2(w0.z, w0.w);
                cv.u[2] = cvtpk2(w1.x, w1.y); cv.u[3] = cvtpk2(w1.z, w1.w);
                bfr = cv.s;
            } else {
                bfr = short8{0,0,0,0,0,0,0,0};
            }
            #pragma unroll
            for (int mt = 0; mt < 2; ++mt) {
                const short8* ap = (const short8*)(smem + V2S_OFF +
                                    (mt * 16 + slot) * 1168 + ktg * 64 + q * 16);
                aco2[mt] = __builtin_amdgcn_mfma_f32_16x16x32_bf16(*ap, bfr, aco2[mt], 0, 0, 0);
            }
        }
        const float bo = bmain[o];
        __syncthreads();
        #pragma unroll
        for (int mt = 0; mt < 2; ++mt)
        #pragma unroll
        for (int r = 0; r < 4; ++r)
            OTB[o * 33 + mt * 16 + q * 4 + r] = aco2[mt][r] + bo;
    }
    __syncthreads();
    #pragma unroll
    for (int i = 0; i < 8; ++i) {
        int f  = i * 256 + tid;
        int oo = f >> 5, pp = f & 31;
        out[(size_t)(b * 64 + oo) * 4096 + (ty0 + (pp >> 3)) * 64 + (tx0 + (pp & 7))] =
            OTB[oo * 33 + pp];
    }
}

extern "C" void kernel_launch(void* const* d_in, const int* in_sizes, int n_in,
                              void* d_out, int out_size, void* d_ws, size_t ws_size,
                              hipStream_t stream) {
    const float* inps   = (const float*)d_in[0];
    const float* weight = (const float*)d_in[1];
    const float* bias   = (const float*)d_in[2];
    const float* woff   = (const float*)d_in[3];
    const float* boff   = (const float*)d_in[4];
    float* outp = (float*)d_out;

    if (ws_size >= WS_NEEDED) {
        unsigned* pw = (unsigned*)d_ws;
        pack_weights<<<dim3(560), dim3(256), 0, stream>>>(weight, woff, pw);
        hipFuncSetAttribute((const void*)deform_v8,
                            hipFuncAttributeMaxDynamicSharedMemorySize, LDS_V8);
        deform_v8<<<dim3(1024), dim3(512), LDS_V8, stream>>>(
            inps, bias, boff,
            (const unsigned short*)pw,
            (const unsigned short*)(pw + PWOFF_U32), outp);
    } else {
        hipFuncSetAttribute((const void*)deform_v2,
                            hipFuncAttributeMaxDynamicSharedMemorySize, V2LDS_BYTES);
        deform_v2<<<dim3(1024), dim3(256), V2LDS_BYTES, stream>>>(
            inps, weight, bias, woff, boff, outp);
    }
}